// Round 18
// baseline (347.270 us; speedup 1.0000x reference)
//
#include <hip/hip_runtime.h>

typedef _Float16 f16x8 __attribute__((ext_vector_type(8)));
typedef _Float16 f16x4 __attribute__((ext_vector_type(4)));
typedef _Float16 f16x2 __attribute__((ext_vector_type(2)));
typedef float f32x4 __attribute__((ext_vector_type(4)));

// ---------------------------------------------------------------------------
// DeformConv stack: 8 layers, N=4, H=W=64.
// L0 (512->256, k=1), L1 (256->128, 3x3), L2..L7 (128->128, 3x3)
// Round-17 certified core (64px x 128co tile, grid.x=256, coalesced A-gather,
// B fragment-direct, fp16 hi/lo 3-term MFMA, XCD swizzle, LDS A-dbuf with one
// lgkm-only barrier/iter, depth-2 consume-before-reissue) with ONE change:
// 1024 THREADS (16 waves) -> 4 waves per SIMD. Wave tile = 32px x 16co
// (px-half wv>>3, co-group wv&7): pixel split, NO K-reassociation.
// A-staging: one 2-channel pair per thread (float2 gather) — same fp32
// combine expressions, same bytes, bit-identical staged values.
// B loads duplicate across the two px-half waves (L2 has headroom).
// NOTE: grid.x>256 / z-splits on 3x3 layers corrupt results (r5/r10,
// mechanism unexplained) — grid shapes stay (256,1)/(256,2) (certified).
// ---------------------------------------------------------------------------

__global__ __launch_bounds__(256) void nchw2nhwc(const float* __restrict__ in,
                                                 float* __restrict__ out, int C) {
    const int ctiles = C >> 5;
    const int ct = blockIdx.x % ctiles;
    const int xt = blockIdx.x / ctiles;
    const int y = blockIdx.y, n = blockIdx.z;
    const int c0 = ct * 32, x0 = xt * 32;
    __shared__ float tile[32][33];
    const int tx = threadIdx.x & 31, tr = threadIdx.x >> 5;
#pragma unroll
    for (int r = 0; r < 32; r += 8) {
        const int c = c0 + tr + r;
        tile[tr + r][tx] = in[(((n * C + c) << 6) + y) * 64 + x0 + tx];
    }
    __syncthreads();
#pragma unroll
    for (int r = 0; r < 32; r += 8) {
        const int x = x0 + tr + r;
        out[((((n << 6) + y) * 64) + x) * C + c0 + tx] = tile[tx][tr + r];
    }
}

__global__ __launch_bounds__(256) void nhwc2nchw(const float* __restrict__ in,
                                                 float* __restrict__ out, int C) {
    const int ctiles = C >> 5;
    const int ct = blockIdx.x % ctiles;
    const int xt = blockIdx.x / ctiles;
    const int y = blockIdx.y, n = blockIdx.z;
    const int c0 = ct * 32, x0 = xt * 32;
    __shared__ float tile[32][33];
    const int tx = threadIdx.x & 31, tr = threadIdx.x >> 5;
#pragma unroll
    for (int r = 0; r < 32; r += 8) {
        const int x = x0 + tr + r;
        tile[tr + r][tx] = in[((((n << 6) + y) * 64) + x) * C + c0 + tx];
    }
    __syncthreads();
#pragma unroll
    for (int r = 0; r < 32; r += 8) {
        const int c = c0 + tr + r;
        out[(((n * C + c) << 6) + y) * 64 + x0 + tx] = tile[tx][tr + r];
    }
}

// w[cout][cin][kh][kw] fp32 -> fragment-ordered fp16 hi/lo rows:
// row r2 = (k*NC+c)*NCO16 + g; 1024 halves per row: [ hi 64x8 | lo 64x8 ].
// lane l holds co = g*16+(l&15), ci = c*32+(l>>4)*8+j  (exact B-frag layout).
__global__ __launch_bounds__(256) void prep_wfrag(const float* __restrict__ w,
                                                  _Float16* __restrict__ wtf,
                                                  int CIN, int COUT, int KK, int total) {
    const int idx = blockIdx.x * 256 + threadIdx.x;
    if (idx >= total) return;
    const int lane = idx & 63;
    int r = idx >> 6;
    const int NCO16 = COUT >> 4;
    const int g = r % NCO16;
    r /= NCO16;                       // r = k*NC + c
    const int NC = CIN >> 5;
    const int co = g * 16 + (lane & 15);
    const int ci0 = (r % NC) * 32 + (lane >> 4) * 8;
    const int k = r / NC;
    f16x8 hv, lv;
#pragma unroll
    for (int j = 0; j < 8; ++j) {
        const float v = w[(co * CIN + ci0 + j) * KK + k];
        const _Float16 h = (_Float16)v;
        hv[j] = h;
        lv[j] = (_Float16)(v - (float)h);
    }
    const size_t base = ((size_t)(r * NCO16 + g)) * 1024 + lane * 8;
    *(f16x8*)&wtf[base] = hv;
    *(f16x8*)&wtf[base + 512] = lv;
}

struct PixSt {
    float w0, w1, w2, w3;
    const float *p00, *p01, *p10, *p11;
};

struct ASet {
    float2 A0[4];   // 4 corners x 2ch
    float cw[4];    // bilinear coef snapshot matching the A data's tap
};

// Deformable conv layer. grid: (256, COUTF/128), block 1024 (16 waves).
// Block tile: 64 px (one image row) x 128 couts. Wave: 32 px x 16 co.
template <int TAPS, int CIN, int COUTF>
__global__ __launch_bounds__(1024) void dconv_mfma(const float* __restrict__ in,
                                                   const float* __restrict__ off,
                                                   const _Float16* __restrict__ wtf,
                                                   const float* __restrict__ bias,
                                                   float* __restrict__ out) {
    constexpr int KS = (TAPS == 9) ? 3 : 1;
    constexpr int PAD = (TAPS == 9) ? 1 : 0;
    constexpr int NC = CIN / 32;          // 32-channel chunks
    constexpr int NCO16 = COUTF / 16;
    constexpr int TOTAL_IT = TAPS * NC;   // even: 16, 72, 36

    // A tile, double-buffered: 2 x 64 rows x stride-40 halves = 20.5 KB
    __shared__ __align__(16) _Float16 sAh[2][64 * 40];
    __shared__ __align__(16) _Float16 sAl[2][64 * 40];

    const int t = threadIdx.x;
    const int bx0 = blockIdx.x;
    const int bx = (bx0 & 7) * 32 + (bx0 >> 3); // bijective XCD swizzle (256=8*32)
    const int coy = blockIdx.y;    // 128-co tile
    const int n = bx >> 6, y = bx & 63;

    // A-staging roles: one pixel per 16 threads (row ppx), channel pair j2
    const int ppx = t >> 4;        // 0..63
    const int j2 = (t & 15) * 2;   // channel pair within 32-ch chunk

    // mfma roles: wave wv = (px-half wv>>3, co-group wv&7)
    const int lane = t & 63, wv = t >> 6;   // wv 0..15
    const int l15 = lane & 15, lq = lane >> 4;
    const int pxh = (wv >> 3) * 32;               // px-half base row
    const int gbase = coy * 8 + (wv & 7);         // B row-group

    PixSt q0;                      // bilinear state (tap of last issue)

    auto mkcoef = [&](PixSt& q, int k, float dy, float dx) {
        const int kh = k / KS, kw = k - kh * KS;
        const float py = (float)(y + kh - PAD) + dy;
        const float pxc = (float)(ppx + kw - PAD) + dx;
        const float y0f = floorf(py), x0f = floorf(pxc);
        const int iy0 = (int)y0f, ix0 = (int)x0f;
        const int iy1 = iy0 + 1, ix1 = ix0 + 1;
        const float wy1 = py - y0f, wy0 = 1.f - wy1;
        const float wx1 = pxc - x0f, wx0 = 1.f - wx1;
        const bool vy0 = (iy0 >= 0) & (iy0 < 64), vy1 = (iy1 >= 0) & (iy1 < 64);
        const bool vx0 = (ix0 >= 0) & (ix0 < 64), vx1 = (ix1 >= 0) & (ix1 < 64);
        q.w0 = (vy0 & vx0) ? wy0 * wx0 : 0.f;
        q.w1 = (vy0 & vx1) ? wy0 * wx1 : 0.f;
        q.w2 = (vy1 & vx0) ? wy1 * wx0 : 0.f;
        q.w3 = (vy1 & vx1) ? wy1 * wx1 : 0.f;
        const int cy0 = min(max(iy0, 0), 63), cy1 = min(max(iy1, 0), 63);
        const int cx0 = min(max(ix0, 0), 63), cx1 = min(max(ix1, 0), 63);
        q.p00 = in + (size_t)(((n << 6) + cy0) * 64 + cx0) * CIN + j2;
        q.p01 = in + (size_t)(((n << 6) + cy0) * 64 + cx1) * CIN + j2;
        q.p10 = in + (size_t)(((n << 6) + cy1) * 64 + cx0) * CIN + j2;
        q.p11 = in + (size_t)(((n << 6) + cy1) * 64 + cx1) * CIN + j2;
    };

    auto oidx = [&](int k) {
        return ((n * 2 * TAPS + 2 * k) * 64 + y) * 64 + ppx;
    };

    ASet S0, S1;                   // depth-2 A register sets
    f16x8 bh0, bl0, bh1, bl1;      // depth-2 B register sets (16 co/wave)

    auto loadA = [&](ASet& S, int c) {
        const int o = c * 32;
        S.A0[0] = *(const float2*)(q0.p00 + o);
        S.A0[1] = *(const float2*)(q0.p01 + o);
        S.A0[2] = *(const float2*)(q0.p10 + o);
        S.A0[3] = *(const float2*)(q0.p11 + o);
        S.cw[0] = q0.w0; S.cw[1] = q0.w1; S.cw[2] = q0.w2; S.cw[3] = q0.w3;
    };

    auto loadB = [&](f16x8& bh, f16x8& bl, int k, int c) {
        const size_t rw = ((size_t)((k * NC + c) * NCO16) + gbase) * 1024 + lane * 8;
        bh = *(const f16x8*)&wtf[rw];
        bl = *(const f16x8*)&wtf[rw + 512];
    };

    auto write_chunk = [&](const ASet& S, int buf) {
        float v0[2];
        v0[0] = S.cw[0] * S.A0[0].x + S.cw[1] * S.A0[1].x + S.cw[2] * S.A0[2].x + S.cw[3] * S.A0[3].x;
        v0[1] = S.cw[0] * S.A0[0].y + S.cw[1] * S.A0[1].y + S.cw[2] * S.A0[2].y + S.cw[3] * S.A0[3].y;
        f16x2 hv0, lv0;
#pragma unroll
        for (int j = 0; j < 2; ++j) {
            const _Float16 h0 = (_Float16)v0[j];
            hv0[j] = h0;
            lv0[j] = (_Float16)(v0[j] - (float)h0);
        }
        *(f16x2*)&sAh[buf][ppx * 40 + j2] = hv0;
        *(f16x2*)&sAl[buf][ppx * 40 + j2] = lv0;
    };

    // prologue: tap0 state; issue iter0 and iter1 loads (both tap0: NC >= 4)
    mkcoef(q0, 0, off[oidx(0)], off[oidx(0) + 4096]);
    float dyn0 = 0.f, dxn0 = 0.f;
    if (TAPS > 1) { dyn0 = off[oidx(1)]; dxn0 = off[oidx(1) + 4096]; }
    loadA(S0, 0); loadB(bh0, bl0, 0, 0);
    loadA(S1, 1); loadB(bh1, bl1, 0, 1);
    int kq = 0, cq = 1;   // (tap, chunk) of last issued load

    f32x4 acc[2] = {};

    auto body = [&](ASet& S, f16x8& bh, f16x8& bl, int buf, int it) {
        write_chunk(S, buf);          // consume S (vmcnt waits auto-inserted)
        const bool more = (it + 2 < TOTAL_IT);
        if (more) {                   // S is free: reload for it+2 (A early)
            int c2 = cq + 1, k2 = kq;
            if (c2 == NC) {
                c2 = 0; k2 = kq + 1;
                mkcoef(q0, k2, dyn0, dxn0);
                if (k2 + 1 < TAPS) {
                    dyn0 = off[oidx(k2 + 1)];
                    dxn0 = off[oidx(k2 + 1) + 4096];
                }
            }
            loadA(S, c2);
            kq = k2; cq = c2;
        }
        // single LDS-only barrier: buf writes visible; prev-buf reads drained
        // by each wave's own lgkmcnt(0); globals stay in flight (T4)
        asm volatile("s_waitcnt lgkmcnt(0)\n\ts_barrier" ::: "memory");

        f16x8 ah[2], al[2];
#pragma unroll
        for (int mi = 0; mi < 2; ++mi) {
            const int ar = pxh + mi * 16 + l15;
            ah[mi] = *(const f16x8*)&sAh[buf][ar * 40 + lq * 8];
            al[mi] = *(const f16x8*)&sAl[buf][ar * 40 + lq * 8];
        }
#pragma unroll
        for (int mi = 0; mi < 2; ++mi) {
            acc[mi] = __builtin_amdgcn_mfma_f32_16x16x32_f16(ah[mi], bh, acc[mi], 0, 0, 0);
            acc[mi] = __builtin_amdgcn_mfma_f32_16x16x32_f16(ah[mi], bl, acc[mi], 0, 0, 0);
            acc[mi] = __builtin_amdgcn_mfma_f32_16x16x32_f16(al[mi], bh, acc[mi], 0, 0, 0);
        }
        if (more) loadB(bh, bl, kq, cq);  // B free after MFMA: reload for it+2
    };

    for (int it = 0; it < TOTAL_IT; it += 2) {
        body(S0, bh0, bl0, 0, it);
        body(S1, bh1, bl1, 1, it + 1);
    }

    // epilogue: bias + ReLU, fp32 NHWC store
    const size_t pixbase = (size_t)bx * 64;
    {
        const int co = coy * 128 + (wv & 7) * 16 + l15;
        const float bv = bias[co];
#pragma unroll
        for (int mi = 0; mi < 2; ++mi) {
#pragma unroll
            for (int r = 0; r < 4; ++r) {
                const int pxl = pxh + mi * 16 + lq * 4 + r;
                out[(pixbase + pxl) * COUTF + co] = fmaxf(acc[mi][r] + bv, 0.f);
            }
        }
    }
}

extern "C" void kernel_launch(void* const* d_in, const int* in_sizes, int n_in,
                              void* d_out, int out_size, void* d_ws, size_t ws_size,
                              hipStream_t stream) {
    (void)in_sizes; (void)n_in; (void)out_size; (void)ws_size;
    const float* x = (const float*)d_in[0];
    const float* offs[8];
    const float* wsrc[8];
    const float* bs[8];
    for (int i = 0; i < 8; ++i) {
        offs[i] = (const float*)d_in[1 + i];
        wsrc[i] = (const float*)d_in[9 + 2 * i];
        bs[i] = (const float*)d_in[10 + 2 * i];
    }
    // workspace: bufA 32MB | bufB 16MB | wt (fp16 hi/lo frag) 5.25MB
    float* bufA = (float*)d_ws;
    float* bufB = (float*)((char*)d_ws + 33554432u);
    _Float16* wt = (_Float16*)((char*)d_ws + 50331648u);
    const size_t wo[8] = {0, 262144, 851968, 1146880, 1441792, 1736704, 2031616, 2326528};
    const int cins[8] = {512, 256, 128, 128, 128, 128, 128, 128};
    const int couts[8] = {256, 128, 128, 128, 128, 128, 128, 128};
    const int kks[8] = {1, 9, 9, 9, 9, 9, 9, 9};

    nchw2nhwc<<<dim3((512 / 32) * 2, 64, 4), 256, 0, stream>>>(x, bufA, 512);
    for (int i = 0; i < 8; ++i) {
        const int total = kks[i] * (cins[i] / 32) * (couts[i] / 16) * 64;
        prep_wfrag<<<(total + 255) / 256, 256, 0, stream>>>(wsrc[i], wt + wo[i],
                                                            cins[i], couts[i], kks[i], total);
    }
    dconv_mfma<1, 512, 256><<<dim3(256, 2), 1024, 0, stream>>>(bufA, offs[0], wt + wo[0], bs[0], bufB);
    dconv_mfma<9, 256, 128><<<dim3(256, 1), 1024, 0, stream>>>(bufB, offs[1], wt + wo[1], bs[1], bufA);
    dconv_mfma<9, 128, 128><<<dim3(256, 1), 1024, 0, stream>>>(bufA, offs[2], wt + wo[2], bs[2], bufB);
    dconv_mfma<9, 128, 128><<<dim3(256, 1), 1024, 0, stream>>>(bufB, offs[3], wt + wo[3], bs[3], bufA);
    dconv_mfma<9, 128, 128><<<dim3(256, 1), 1024, 0, stream>>>(bufA, offs[4], wt + wo[4], bs[4], bufB);
    dconv_mfma<9, 128, 128><<<dim3(256, 1), 1024, 0, stream>>>(bufB, offs[5], wt + wo[5], bs[5], bufA);
    dconv_mfma<9, 128, 128><<<dim3(256, 1), 1024, 0, stream>>>(bufA, offs[6], wt + wo[6], bs[6], bufB);
    dconv_mfma<9, 128, 128><<<dim3(256, 1), 1024, 0, stream>>>(bufB, offs[7], wt + wo[7], bs[7], bufA);
    nhwc2nchw<<<dim3((128 / 32) * 2, 64, 4), 256, 0, stream>>>(bufA, (float*)d_out, 128);
}

// Round 19
// 267.964 us; speedup vs baseline: 1.2960x; 1.2960x over previous
//
#include <hip/hip_runtime.h>

typedef _Float16 f16x8 __attribute__((ext_vector_type(8)));
typedef _Float16 f16x4 __attribute__((ext_vector_type(4)));
typedef float f32x4 __attribute__((ext_vector_type(4)));

// ---------------------------------------------------------------------------
// DeformConv stack: 8 layers, N=4, H=W=64.
// L0 (512->256, k=1), L1 (256->128, 3x3), L2..L7 (128->128, 3x3)
// Round-17 certified core (64px x 128co tile, 512 thr = 2 waves/SIMD,
// grid.x=256, coalesced A-gather, B fragment-direct, fp16 hi/lo 3-term MFMA,
// XCD swizzle, LDS A-dbuf, single lgkm-only barrier per phase) with ONE
// change: BK=64 PAIR-PHASES. Each barrier phase stages and consumes TWO
// 32-ch chunks (tap-aligned pair: NC even), halving phase count (L1 72->36)
// and amortizing barrier/turnaround. Depth-1 pair prefetch (consume-before-
// reissue) gives A loads a full phase of flight; register budget ~100 keeps
// 2 waves/SIMD (r11's spill trap avoided: one A-set, B reloaded post-MFMA).
// Same staged values, same ascending chunk order per acc -> bit-identical.
// r18 lesson: 1024 thr halves gather width + doubles staging VALU — avoid.
// NOTE: grid.x>256 / z-splits on 3x3 layers corrupt results (r5/r10,
// mechanism unexplained) — grid shapes stay (256,1)/(256,2) (certified).
// ---------------------------------------------------------------------------

__global__ __launch_bounds__(256) void nchw2nhwc(const float* __restrict__ in,
                                                 float* __restrict__ out, int C) {
    const int ctiles = C >> 5;
    const int ct = blockIdx.x % ctiles;
    const int xt = blockIdx.x / ctiles;
    const int y = blockIdx.y, n = blockIdx.z;
    const int c0 = ct * 32, x0 = xt * 32;
    __shared__ float tile[32][33];
    const int tx = threadIdx.x & 31, tr = threadIdx.x >> 5;
#pragma unroll
    for (int r = 0; r < 32; r += 8) {
        const int c = c0 + tr + r;
        tile[tr + r][tx] = in[(((n * C + c) << 6) + y) * 64 + x0 + tx];
    }
    __syncthreads();
#pragma unroll
    for (int r = 0; r < 32; r += 8) {
        const int x = x0 + tr + r;
        out[((((n << 6) + y) * 64) + x) * C + c0 + tx] = tile[tx][tr + r];
    }
}

__global__ __launch_bounds__(256) void nhwc2nchw(const float* __restrict__ in,
                                                 float* __restrict__ out, int C) {
    const int ctiles = C >> 5;
    const int ct = blockIdx.x % ctiles;
    const int xt = blockIdx.x / ctiles;
    const int y = blockIdx.y, n = blockIdx.z;
    const int c0 = ct * 32, x0 = xt * 32;
    __shared__ float tile[32][33];
    const int tx = threadIdx.x & 31, tr = threadIdx.x >> 5;
#pragma unroll
    for (int r = 0; r < 32; r += 8) {
        const int x = x0 + tr + r;
        tile[tr + r][tx] = in[((((n << 6) + y) * 64) + x) * C + c0 + tx];
    }
    __syncthreads();
#pragma unroll
    for (int r = 0; r < 32; r += 8) {
        const int c = c0 + tr + r;
        out[(((n * C + c) << 6) + y) * 64 + x0 + tx] = tile[tx][tr + r];
    }
}

// w[cout][cin][kh][kw] fp32 -> fragment-ordered fp16 hi/lo rows:
// row r2 = (k*NC+c)*NCO16 + g; 1024 halves per row: [ hi 64x8 | lo 64x8 ].
// lane l holds co = g*16+(l&15), ci = c*32+(l>>4)*8+j  (exact B-frag layout).
__global__ __launch_bounds__(256) void prep_wfrag(const float* __restrict__ w,
                                                  _Float16* __restrict__ wtf,
                                                  int CIN, int COUT, int KK, int total) {
    const int idx = blockIdx.x * 256 + threadIdx.x;
    if (idx >= total) return;
    const int lane = idx & 63;
    int r = idx >> 6;
    const int NCO16 = COUT >> 4;
    const int g = r % NCO16;
    r /= NCO16;                       // r = k*NC + c
    const int NC = CIN >> 5;
    const int co = g * 16 + (lane & 15);
    const int ci0 = (r % NC) * 32 + (lane >> 4) * 8;
    const int k = r / NC;
    f16x8 hv, lv;
#pragma unroll
    for (int j = 0; j < 8; ++j) {
        const float v = w[(co * CIN + ci0 + j) * KK + k];
        const _Float16 h = (_Float16)v;
        hv[j] = h;
        lv[j] = (_Float16)(v - (float)h);
    }
    const size_t base = ((size_t)(r * NCO16 + g)) * 1024 + lane * 8;
    *(f16x8*)&wtf[base] = hv;
    *(f16x8*)&wtf[base + 512] = lv;
}

struct PixSt {
    float w0, w1, w2, w3;
    const float *p00, *p01, *p10, *p11;
};

struct ASet {
    float4 Aa[4], Ab[4];   // pair: chunk a and chunk b, 4 corners x 4ch each
    float cw[4];           // coef snapshot (pair is tap-aligned: one set)
};

// Deformable conv layer. grid: (256, COUTF/128), block 512 (8 waves).
// Block tile: 64 px (one image row) x 128 couts. Wave: 64 px x 16 co.
// Phase = 64-channel pair (2 chunks), one lgkm-only barrier per phase.
template <int TAPS, int CIN, int COUTF>
__global__ __launch_bounds__(512) void dconv_mfma(const float* __restrict__ in,
                                                  const float* __restrict__ off,
                                                  const _Float16* __restrict__ wtf,
                                                  const float* __restrict__ bias,
                                                  float* __restrict__ out) {
    constexpr int KS = (TAPS == 9) ? 3 : 1;
    constexpr int PAD = (TAPS == 9) ? 1 : 0;
    constexpr int NC = CIN / 32;          // 32-channel chunks (even: 16, 8, 4)
    constexpr int NCO16 = COUTF / 16;
    constexpr int NPAIR = TAPS * NC / 2;  // even: 8, 36, 18

    // A tile: [buf][chunk-slot][64 rows x stride-40], 40 KB total
    __shared__ __align__(16) _Float16 sAh[2][2][64 * 40];
    __shared__ __align__(16) _Float16 sAl[2][2][64 * 40];

    const int t = threadIdx.x;
    const int bx0 = blockIdx.x;
    const int bx = (bx0 & 7) * 32 + (bx0 >> 3); // bijective XCD swizzle (256=8*32)
    const int coy = blockIdx.y;    // 128-co tile
    const int n = bx >> 6, y = bx & 63;

    // A-staging roles: one pixel per 8 threads (row ppx), channel quad j4
    const int ppx = t >> 3;        // 0..63
    const int j4 = (t & 7) * 4;

    // mfma roles: wave wv owns 16-co group, all 64 px
    const int lane = t & 63, wv = t >> 6;   // wv 0..7
    const int l15 = lane & 15, lq = lane >> 4;
    const int gbase = coy * 8 + wv;         // B row-group

    PixSt q0;                      // bilinear state (tap of last issue)

    auto mkcoef = [&](PixSt& q, int k, float dy, float dx) {
        const int kh = k / KS, kw = k - kh * KS;
        const float py = (float)(y + kh - PAD) + dy;
        const float pxc = (float)(ppx + kw - PAD) + dx;
        const float y0f = floorf(py), x0f = floorf(pxc);
        const int iy0 = (int)y0f, ix0 = (int)x0f;
        const int iy1 = iy0 + 1, ix1 = ix0 + 1;
        const float wy1 = py - y0f, wy0 = 1.f - wy1;
        const float wx1 = pxc - x0f, wx0 = 1.f - wx1;
        const bool vy0 = (iy0 >= 0) & (iy0 < 64), vy1 = (iy1 >= 0) & (iy1 < 64);
        const bool vx0 = (ix0 >= 0) & (ix0 < 64), vx1 = (ix1 >= 0) & (ix1 < 64);
        q.w0 = (vy0 & vx0) ? wy0 * wx0 : 0.f;
        q.w1 = (vy0 & vx1) ? wy0 * wx1 : 0.f;
        q.w2 = (vy1 & vx0) ? wy1 * wx0 : 0.f;
        q.w3 = (vy1 & vx1) ? wy1 * wx1 : 0.f;
        const int cy0 = min(max(iy0, 0), 63), cy1 = min(max(iy1, 0), 63);
        const int cx0 = min(max(ix0, 0), 63), cx1 = min(max(ix1, 0), 63);
        q.p00 = in + (size_t)(((n << 6) + cy0) * 64 + cx0) * CIN + j4;
        q.p01 = in + (size_t)(((n << 6) + cy0) * 64 + cx1) * CIN + j4;
        q.p10 = in + (size_t)(((n << 6) + cy1) * 64 + cx0) * CIN + j4;
        q.p11 = in + (size_t)(((n << 6) + cy1) * 64 + cx1) * CIN + j4;
    };

    auto oidx = [&](int k) {
        return ((n * 2 * TAPS + 2 * k) * 64 + y) * 64 + ppx;
    };

    ASet S;                        // depth-1 pair A register set
    f16x8 bha, bla, bhb, blb;      // B fragments for current pair

    auto loadA = [&](int cc) {     // cc = within-tap chunk of pair start
        const int oa = cc * 32, ob = oa + 32;
        S.Aa[0] = *(const float4*)(q0.p00 + oa);
        S.Aa[1] = *(const float4*)(q0.p01 + oa);
        S.Aa[2] = *(const float4*)(q0.p10 + oa);
        S.Aa[3] = *(const float4*)(q0.p11 + oa);
        S.Ab[0] = *(const float4*)(q0.p00 + ob);
        S.Ab[1] = *(const float4*)(q0.p01 + ob);
        S.Ab[2] = *(const float4*)(q0.p10 + ob);
        S.Ab[3] = *(const float4*)(q0.p11 + ob);
        S.cw[0] = q0.w0; S.cw[1] = q0.w1; S.cw[2] = q0.w2; S.cw[3] = q0.w3;
    };

    auto loadB = [&](int k, int cc) {
        const size_t ra = ((size_t)((k * NC + cc) * NCO16) + gbase) * 1024 + lane * 8;
        bha = *(const f16x8*)&wtf[ra];
        bla = *(const f16x8*)&wtf[ra + 512];
        const size_t rb = ra + (size_t)NCO16 * 1024;
        bhb = *(const f16x8*)&wtf[rb];
        blb = *(const f16x8*)&wtf[rb + 512];
    };

    auto stage_half = [&](const float4* A, const float* cw, int buf, int sl) {
        float v0[4];
        v0[0] = cw[0] * A[0].x + cw[1] * A[1].x + cw[2] * A[2].x + cw[3] * A[3].x;
        v0[1] = cw[0] * A[0].y + cw[1] * A[1].y + cw[2] * A[2].y + cw[3] * A[3].y;
        v0[2] = cw[0] * A[0].z + cw[1] * A[1].z + cw[2] * A[2].z + cw[3] * A[3].z;
        v0[3] = cw[0] * A[0].w + cw[1] * A[1].w + cw[2] * A[2].w + cw[3] * A[3].w;
        f16x4 hv0, lv0;
#pragma unroll
        for (int j = 0; j < 4; ++j) {
            const _Float16 h0 = (_Float16)v0[j];
            hv0[j] = h0;
            lv0[j] = (_Float16)(v0[j] - (float)h0);
        }
        *(f16x4*)&sAh[buf][sl][ppx * 40 + j4] = hv0;
        *(f16x4*)&sAl[buf][sl][ppx * 40 + j4] = lv0;
    };

    // prologue: tap0 state; issue pair 0 (chunks 0,1 — tap0 since NC >= 4)
    mkcoef(q0, 0, off[oidx(0)], off[oidx(0) + 4096]);
    float dyn0 = 0.f, dxn0 = 0.f;
    if (TAPS > 1) { dyn0 = off[oidx(1)]; dxn0 = off[oidx(1) + 4096]; }
    loadA(0);
    loadB(0, 0);
    int kq = 0, ccq = 0;   // (tap, within-tap chunk) of last issued pair

    f32x4 acc[4] = {};

    auto body = [&](int buf, int p) {
        stage_half(S.Aa, S.cw, buf, 0);   // consume S (vmcnt waits auto)
        stage_half(S.Ab, S.cw, buf, 1);
        const bool more = (p + 1 < NPAIR);
        if (more) {                       // S free: reload for pair p+1
            const int g = 2 * (p + 1);
            const int k2 = g / NC, cc2 = g % NC;
            if (k2 != kq) {
                mkcoef(q0, k2, dyn0, dxn0);
                if (k2 + 1 < TAPS) {
                    dyn0 = off[oidx(k2 + 1)];
                    dxn0 = off[oidx(k2 + 1) + 4096];
                }
                kq = k2;
            }
            loadA(cc2);
            ccq = cc2;
        }
        // single LDS-only barrier: buf writes visible; prev-buf reads drained
        // by each wave's own lgkmcnt(0); globals stay in flight (T4)
        asm volatile("s_waitcnt lgkmcnt(0)\n\ts_barrier" ::: "memory");

        // chunk a
        {
            f16x8 ah[4], al[4];
#pragma unroll
            for (int mi = 0; mi < 4; ++mi) {
                const int ar = mi * 16 + l15;
                ah[mi] = *(const f16x8*)&sAh[buf][0][ar * 40 + lq * 8];
                al[mi] = *(const f16x8*)&sAl[buf][0][ar * 40 + lq * 8];
            }
#pragma unroll
            for (int mi = 0; mi < 4; ++mi) {
                acc[mi] = __builtin_amdgcn_mfma_f32_16x16x32_f16(ah[mi], bha, acc[mi], 0, 0, 0);
                acc[mi] = __builtin_amdgcn_mfma_f32_16x16x32_f16(ah[mi], bla, acc[mi], 0, 0, 0);
                acc[mi] = __builtin_amdgcn_mfma_f32_16x16x32_f16(al[mi], bha, acc[mi], 0, 0, 0);
            }
        }
        // chunk b
        {
            f16x8 ah[4], al[4];
#pragma unroll
            for (int mi = 0; mi < 4; ++mi) {
                const int ar = mi * 16 + l15;
                ah[mi] = *(const f16x8*)&sAh[buf][1][ar * 40 + lq * 8];
                al[mi] = *(const f16x8*)&sAl[buf][1][ar * 40 + lq * 8];
            }
#pragma unroll
            for (int mi = 0; mi < 4; ++mi) {
                acc[mi] = __builtin_amdgcn_mfma_f32_16x16x32_f16(ah[mi], bhb, acc[mi], 0, 0, 0);
                acc[mi] = __builtin_amdgcn_mfma_f32_16x16x32_f16(ah[mi], blb, acc[mi], 0, 0, 0);
                acc[mi] = __builtin_amdgcn_mfma_f32_16x16x32_f16(al[mi], bhb, acc[mi], 0, 0, 0);
            }
        }
        if (more) loadB(kq, ccq);         // B free after MFMA: reload next pair
    };

    for (int p = 0; p < NPAIR; p += 2) {
        body(0, p);
        body(1, p + 1);
    }

    // epilogue: bias + ReLU, fp32 NHWC store
    const size_t pixbase = (size_t)bx * 64;
    {
        const int co = coy * 128 + wv * 16 + l15;
        const float bv = bias[co];
#pragma unroll
        for (int mi = 0; mi < 4; ++mi) {
#pragma unroll
            for (int r = 0; r < 4; ++r) {
                const int pxl = mi * 16 + lq * 4 + r;
                out[(pixbase + pxl) * COUTF + co] = fmaxf(acc[mi][r] + bv, 0.f);
            }
        }
    }
}

extern "C" void kernel_launch(void* const* d_in, const int* in_sizes, int n_in,
                              void* d_out, int out_size, void* d_ws, size_t ws_size,
                              hipStream_t stream) {
    (void)in_sizes; (void)n_in; (void)out_size; (void)ws_size;
    const float* x = (const float*)d_in[0];
    const float* offs[8];
    const float* wsrc[8];
    const float* bs[8];
    for (int i = 0; i < 8; ++i) {
        offs[i] = (const float*)d_in[1 + i];
        wsrc[i] = (const float*)d_in[9 + 2 * i];
        bs[i] = (const float*)d_in[10 + 2 * i];
    }
    // workspace: bufA 32MB | bufB 16MB | wt (fp16 hi/lo frag) 5.25MB
    float* bufA = (float*)d_ws;
    float* bufB = (float*)((char*)d_ws + 33554432u);
    _Float16* wt = (_Float16*)((char*)d_ws + 50331648u);
    const size_t wo[8] = {0, 262144, 851968, 1146880, 1441792, 1736704, 2031616, 2326528};
    const int cins[8] = {512, 256, 128, 128, 128, 128, 128, 128};
    const int couts[8] = {256, 128, 128, 128, 128, 128, 128, 128};
    const int kks[8] = {1, 9, 9, 9, 9, 9, 9, 9};

    nchw2nhwc<<<dim3((512 / 32) * 2, 64, 4), 256, 0, stream>>>(x, bufA, 512);
    for (int i = 0; i < 8; ++i) {
        const int total = kks[i] * (cins[i] / 32) * (couts[i] / 16) * 64;
        prep_wfrag<<<(total + 255) / 256, 256, 0, stream>>>(wsrc[i], wt + wo[i],
                                                            cins[i], couts[i], kks[i], total);
    }
    dconv_mfma<1, 512, 256><<<dim3(256, 2), 512, 0, stream>>>(bufA, offs[0], wt + wo[0], bs[0], bufB);
    dconv_mfma<9, 256, 128><<<dim3(256, 1), 512, 0, stream>>>(bufB, offs[1], wt + wo[1], bs[1], bufA);
    dconv_mfma<9, 128, 128><<<dim3(256, 1), 512, 0, stream>>>(bufA, offs[2], wt + wo[2], bs[2], bufB);
    dconv_mfma<9, 128, 128><<<dim3(256, 1), 512, 0, stream>>>(bufB, offs[3], wt + wo[3], bs[3], bufA);
    dconv_mfma<9, 128, 128><<<dim3(256, 1), 512, 0, stream>>>(bufA, offs[4], wt + wo[4], bs[4], bufB);
    dconv_mfma<9, 128, 128><<<dim3(256, 1), 512, 0, stream>>>(bufB, offs[5], wt + wo[5], bs[5], bufA);
    dconv_mfma<9, 128, 128><<<dim3(256, 1), 512, 0, stream>>>(bufA, offs[6], wt + wo[6], bs[6], bufB);
    dconv_mfma<9, 128, 128><<<dim3(256, 1), 512, 0, stream>>>(bufB, offs[7], wt + wo[7], bs[7], bufA);
    nhwc2nchw<<<dim3((128 / 32) * 2, 64, 4), 256, 0, stream>>>(bufA, (float*)d_out, 128);
}